// Round 1
// baseline (129.000 us; speedup 1.0000x reference)
//
#include <hip/hip_runtime.h>

// out[b,i,j] = c * sum_{p,q} k[p][q] * inp[b, i+p, j+q]
// where c = vt(I=1) from the LIF scan (linear in I; spike/clamp provably
// inactive since I < 9 < 14 over 1000 steps => v stays < 14 always).

#define ROWS 32

__global__ __launch_bounds__(256) void snn_conv_box_kernel(
    const float* __restrict__ inp, const float* __restrict__ kw,
    float* __restrict__ out, float c)
{
    const int W = 512, H = 512, OW = 510, OH = 510;
    (void)H;
    int j  = blockIdx.x * 256 + threadIdx.x;   // output column 0..509
    int b  = blockIdx.z;                       // batch
    int i0 = blockIdx.y * ROWS;                // first output row of strip
    if (j >= OW) return;

    float k00 = kw[0], k01 = kw[1], k02 = kw[2];
    float k10 = kw[3], k11 = kw[4], k12 = kw[5];
    float k20 = kw[6], k21 = kw[7], k22 = kw[8];

    const float* ip = inp + ((size_t)b * W + i0) * W + j;   // H==W==512
    float*       op = out + ((size_t)b * OH + i0) * OW + j;

    // Pipeline warm-up: weighted horizontal sums of input rows i0, i0+1.
    float x0, x1, x2;
    x0 = ip[0]; x1 = ip[1]; x2 = ip[2];
    float acc2 = k00 * x0 + k01 * x1 + k02 * x2;            // h0(i0)
    x0 = ip[W]; x1 = ip[W + 1]; x2 = ip[W + 2];
    float acc1 = k00 * x0 + k01 * x1 + k02 * x2;            // h0(i0+1)
    acc2 += k10 * x0 + k11 * x1 + k12 * x2;                 // + h1(i0+1)

    int nrows = min(ROWS, OH - i0);
    for (int r = 0; r < nrows; ++r) {
        const float* p = ip + (size_t)(r + 2) * W;
        x0 = p[0]; x1 = p[1]; x2 = p[2];
        float t2 = k20 * x0 + k21 * x1 + k22 * x2;          // h2(row r+2)
        op[(size_t)r * OW] = (acc2 + t2) * c;
        acc2 = acc1 + (k10 * x0 + k11 * x1 + k12 * x2);     // h0(r+1)+h1(r+2)
        acc1 =         k00 * x0 + k01 * x1 + k02 * x2;      // h0(r+2)
    }
}

extern "C" void kernel_launch(void* const* d_in, const int* in_sizes, int n_in,
                              void* d_out, int out_size, void* d_ws, size_t ws_size,
                              hipStream_t stream) {
    (void)in_sizes; (void)n_in; (void)d_ws; (void)ws_size; (void)out_size;
    const float* inp = (const float*)d_in[0];
    const float* kw  = (const float*)d_in[1];
    float* out = (float*)d_out;

    // Closed-form LIF scan with I = 1 (double precision; exact by linearity).
    // v0 = lif_step(0, 1); then 999 iterations of body.
    double v = 0.0;
    v = v + (3000.0 * 1.0 - v) / 30000.0 * 0.01;   // = 0.001
    double vt = v;
    for (int i = 0; i < 999; ++i) {
        v  = v + (3000.0 - v) / 30000.0 * 0.01;
        vt = (v + vt) / 1000.0;
    }
    float c = (float)vt;   // ~0.99983...

    dim3 block(256, 1, 1);
    dim3 grid((510 + 255) / 256, (510 + ROWS - 1) / ROWS, 64);  // 2 x 16 x 64
    hipLaunchKernelGGL(snn_conv_box_kernel, grid, block, 0, stream,
                       inp, kw, out, c);
}

// Round 2
// 121.974 us; speedup vs baseline: 1.0576x; 1.0576x over previous
//
#include <hip/hip_runtime.h>

// out[b,i,j] = c * sum_{p,q} k[p][q] * inp[b, i+p, j+q]
// c = vt(I=1) from the LIF scan (linear in I; spike/clamp provably inactive
// since I < 9 < 14 for all 1000 steps).
//
// Each thread: 4 output columns x ROWS output rows, rolling vertical
// line-buffer in registers. Per row: one float4 + one float2 load (24B),
// two float2 stores. Out-row stride 510*4 = 2040 B (8B-aligned), in-row
// stride 2048 B (16B-aligned) -> all vector accesses naturally aligned.

#define ROWS 16

__global__ __launch_bounds__(256) void snn_conv_box_kernel(
    const float* __restrict__ inp, const float* __restrict__ kw,
    float* __restrict__ out, float c)
{
    const int W = 512, OW = 510, OH = 510;
    int tx = threadIdx.x & 127;          // column group: cols 4*tx .. 4*tx+3
    int ty = threadIdx.x >> 7;           // row sub-strip 0/1
    int j  = tx << 2;
    int b  = blockIdx.z;
    int i0 = (blockIdx.y * 2 + ty) * ROWS;

    float k00 = kw[0], k01 = kw[1], k02 = kw[2];
    float k10 = kw[3], k11 = kw[4], k12 = kw[5];
    float k20 = kw[6], k21 = kw[7], k22 = kw[8];

    const float* ip = inp + ((size_t)(b * W + i0)) * W + j;
    float*       op = out + ((size_t)b * OH + i0) * OW + j;
    const bool edge = (tx == 127);       // cols 508..511: only 508,509 valid; s4,s5 unused

    float s0, s1, s2, s3, s4, s5;
#define LOADROW(p)                                            \
    {   float4 _v = *(const float4*)(p);                      \
        s0 = _v.x; s1 = _v.y; s2 = _v.z; s3 = _v.w;           \
        if (!edge) { float2 _e = *(const float2*)((p) + 4);   \
                     s4 = _e.x; s5 = _e.y; }                  \
        else { s4 = 0.f; s5 = 0.f; } }

    // Warm-up: h-sums of input rows i0 and i0+1.
    float a2x, a2y, a2z, a2w, a1x, a1y, a1z, a1w;
    LOADROW(ip);
    a2x = k00*s0 + k01*s1 + k02*s2;
    a2y = k00*s1 + k01*s2 + k02*s3;
    a2z = k00*s2 + k01*s3 + k02*s4;
    a2w = k00*s3 + k01*s4 + k02*s5;
    LOADROW(ip + W);
    a1x = k00*s0 + k01*s1 + k02*s2;
    a1y = k00*s1 + k01*s2 + k02*s3;
    a1z = k00*s2 + k01*s3 + k02*s4;
    a1w = k00*s3 + k01*s4 + k02*s5;
    a2x += k10*s0 + k11*s1 + k12*s2;
    a2y += k10*s1 + k11*s2 + k12*s3;
    a2z += k10*s2 + k11*s3 + k12*s4;
    a2w += k10*s3 + k11*s4 + k12*s5;

    int nrows = min(ROWS, OH - i0);
#pragma unroll 4
    for (int r = 0; r < nrows; ++r) {
        const float* p = ip + (size_t)(r + 2) * W;
        LOADROW(p);
        float h2x = k20*s0 + k21*s1 + k22*s2;
        float h2y = k20*s1 + k21*s2 + k22*s3;
        float h2z = k20*s2 + k21*s3 + k22*s4;
        float h2w = k20*s3 + k21*s4 + k22*s5;

        float* q = op + (size_t)r * OW;
        float2 lo; lo.x = (a2x + h2x) * c; lo.y = (a2y + h2y) * c;
        *(float2*)q = lo;
        if (!edge) {
            float2 hi; hi.x = (a2z + h2z) * c; hi.y = (a2w + h2w) * c;
            *(float2*)(q + 2) = hi;
        }

        float h1x = k10*s0 + k11*s1 + k12*s2;
        float h1y = k10*s1 + k11*s2 + k12*s3;
        float h1z = k10*s2 + k11*s3 + k12*s4;
        float h1w = k10*s3 + k11*s4 + k12*s5;
        a2x = a1x + h1x; a2y = a1y + h1y;
        a2z = a1z + h1z; a2w = a1w + h1w;
        a1x = k00*s0 + k01*s1 + k02*s2;
        a1y = k00*s1 + k01*s2 + k02*s3;
        a1z = k00*s2 + k01*s3 + k02*s4;
        a1w = k00*s3 + k01*s4 + k02*s5;
    }
#undef LOADROW
}

extern "C" void kernel_launch(void* const* d_in, const int* in_sizes, int n_in,
                              void* d_out, int out_size, void* d_ws, size_t ws_size,
                              hipStream_t stream) {
    (void)in_sizes; (void)n_in; (void)d_ws; (void)ws_size; (void)out_size;
    const float* inp = (const float*)d_in[0];
    const float* kw  = (const float*)d_in[1];
    float* out = (float*)d_out;

    // Closed-form LIF scan with I = 1 (double precision; exact by linearity).
    double v = 0.0;
    v = v + (3000.0 * 1.0 - v) / 30000.0 * 0.01;   // = 0.001
    double vt = v;
    for (int i = 0; i < 999; ++i) {
        v  = v + (3000.0 - v) / 30000.0 * 0.01;
        vt = (v + vt) / 1000.0;
    }
    float c = (float)vt;   // ~0.99983...

    dim3 block(256, 1, 1);
    dim3 grid(1, (510 + 2 * ROWS - 1) / (2 * ROWS), 64);   // 1 x 16 x 64
    hipLaunchKernelGGL(snn_conv_box_kernel, grid, block, 0, stream,
                       inp, kw, out, c);
}